// Round 8
// baseline (46.266 us; speedup 1.0000x reference)
//
#include <hip/hip_runtime.h>
#include <hip/hip_bf16.h>

// SHConv via bf16 MFMA: out[b,o,n] = sum_i x[b,i,n] * W_{l(n)}[i,o], l(n)=floor(sqrt(n))
// x: (32,64,6561) f32, weight: (64,64,17,1) f32, out: (32,64,6561) f32
//
// R7 = R6 with the last-window stage clamp FIXED: the LDS destination now shifts
// together with the clamped global source (lp = np - n0), keeping data
// position-aligned. Duplicate same-value LDS writes from clamped lanes are benign.
//
//  Region B (n >= 1024, l >= 32): global-n-aligned 128-position windows (zero pad).
//    stage: float4 loads (512B runs) -> bf16 LDS xs[pos][ch]
//    compute: per-degree pieces (<=3/window), boundary chunks recomputed per degree,
//             masked os writes; MFMA core identical to verified R3.
//    store: fp32 LDS os[o][pos] -> float4 stores (512B runs, full-line writes)
//  Region A (l < 32): verified R3 direct 16-chunk kernel, slot map for l<32 only.

#define NTOT 6561
#define NL   81
#define CH   64
#define WTB_BYTES (NL * CH * CH * 2)     // 663552
#define NWINB 44                         // 128-pos windows covering [1024, 6561)
#define GXA   20                         // region A: 80 slots / 4 waves per block
#define GXT   (NWINB + GXA)              // 64

typedef __attribute__((ext_vector_type(8))) short bf16x8;
typedef __attribute__((ext_vector_type(4))) float f32x4;

// ---- Kernel A: bf16 interpolated weight table, wtb[l][o][i] (i contiguous) ----
__global__ __launch_bounds__(256) void interp_bf16(const float* __restrict__ w,
                                                   __hip_bfloat16* __restrict__ wtb) {
  int idx = blockIdx.x * 256 + threadIdx.x;   // 1296*256 = 331776 exact
  int l = idx >> 12;
  int o = (idx >> 6) & 63;
  int i = idx & 63;
  int cp; float f;
  if (l < 75) { cp = l / 5; f = (float)(l - cp * 5) * 0.2f; }
  else        { cp = 15;    f = (float)(l - 75) * 0.2f; }
  const float* wp = w + (size_t)(i * 64 + o) * 17 + cp;   // weight[i][o][cp]
  float v = (1.0f - f) * wp[0] + f * wp[1];
  wtb[(size_t)l * 4096 + o * 64 + i] = __float2bfloat16(v);
}

__device__ __forceinline__ int isqrt_dev(int n) {
  int r = (int)sqrtf((float)n);
  while ((r + 1) * (r + 1) <= n) ++r;
  while (r * r > n) --r;
  return r;
}

// ---- fused main kernel: grid (64, 32), 256 threads ----
__global__ __launch_bounds__(256) void shconv_fused(const float* __restrict__ x,
                                                    const __hip_bfloat16* __restrict__ wtb,
                                                    float* __restrict__ out) {
  __shared__ __hip_bfloat16 xs[128][66];   // [pos][ch] bf16, pitch 66 (132B rows)
  __shared__ float os[64][132];            // [o][pos] fp32, pitch 132 dw (16B-aligned rows)

  const int tid  = threadIdx.x;
  const int wv   = tid >> 6;
  const int lane = tid & 63;
  const int m    = lane & 15;
  const int kg   = lane >> 4;
  const int b    = blockIdx.y;

  if (blockIdx.x < NWINB) {
    // ================= Region B: n in [1024, 6561), 128-pos windows =================
    const int n0    = 1024 + (int)blockIdx.x * 128;
    const int valid = min(128, NTOT - n0);

    // ---- stage: float4 loads (512B contiguous runs), transpose to bf16 LDS ----
    {
      const float* xb = x + (size_t)b * CH * NTOT;
      const int qs  = lane & 31;                 // quad index within window
      const int chb = (wv << 4) + (lane >> 5);   // base channel for this lane
      int np = n0 + 4 * qs;
      int lp = 4 * qs;                           // local LDS position of v.x
      if (np > NTOT - 4) {                       // last window: shift BOTH src and dst
        lp -= np - (NTOT - 4);                   // keeps xs[lp+j] = x[n0+lp+j] aligned
        np = NTOT - 4;                           // (dup same-value LDS writes: benign)
      }
#pragma unroll
      for (int u = 0; u < 8; ++u) {
        const int ch = chb + (u << 1);           // wave covers ch [wv*16, wv*16+16)
        float4 v;
        __builtin_memcpy(&v, xb + (size_t)ch * NTOT + np, 16);
        xs[lp + 0][ch] = __float2bfloat16(v.x);
        xs[lp + 1][ch] = __float2bfloat16(v.y);
        xs[lp + 2][ch] = __float2bfloat16(v.z);
        xs[lp + 3][ch] = __float2bfloat16(v.w);
      }
    }
    __syncthreads();

    // ---- compute: block-uniform degree-piece loop, wave owns chunks 2wv, 2wv+1 ----
    int lcur = isqrt_dev(n0);
    int pa = 0;
    while (pa < valid) {
      int pb = (lcur + 1) * (lcur + 1) - n0;
      if (pb > valid) pb = valid;
      const __hip_bfloat16* wl = wtb + (size_t)lcur * 4096;
#pragma unroll
      for (int kk = 0; kk < 2; ++kk) {
        const int k0 = (wv * 2 + kk) * 16;
        if (k0 + 16 > pa && k0 < pb) {           // chunk overlaps piece
          const int p = k0 + m;                  // local position (B col)
          bf16x8 bf[2];
#pragma unroll
          for (int ks = 0; ks < 2; ++ks) {
            const int i0 = ks * 32 + kg * 8;
            __builtin_memcpy(&bf[ks], &xs[p][i0], 16);   // 4B-aligned LDS read
          }
          f32x4 acc[4];
#pragma unroll
          for (int t = 0; t < 4; ++t) acc[t] = (f32x4)(0.0f);
#pragma unroll
          for (int ks = 0; ks < 2; ++ks) {
#pragma unroll
            for (int t = 0; t < 4; ++t) {
              const int o  = t * 16 + m;
              const int i0 = ks * 32 + kg * 8;
              bf16x8 afrag = *reinterpret_cast<const bf16x8*>(wl + (size_t)o * 64 + i0);
              acc[t] = __builtin_amdgcn_mfma_f32_16x16x32_bf16(afrag, bf[ks], acc[t], 0, 0, 0);
            }
          }
          // D layout (verified): col = m (position), row = kg*4+rg per 16-row tile
          if (p >= pa && p < pb) {
#pragma unroll
            for (int t = 0; t < 4; ++t)
#pragma unroll
              for (int rg = 0; rg < 4; ++rg)
                os[t * 16 + kg * 4 + rg][p] = acc[t][rg];
          }
        }
      }
      pa = pb;
      ++lcur;
    }
    __syncthreads();

    // ---- store: float4 stores (512B contiguous runs), masked at window tail ----
    {
      float* ob = out + (size_t)b * CH * NTOT;
      const int s4  = (lane & 31) * 4;
      const int obc = (wv << 4) + (lane >> 5);
#pragma unroll
      for (int u = 0; u < 8; ++u) {
        const int o = obc + (u << 1);
        if (s4 + 4 <= valid) {
          float4 v = *(const float4*)&os[o][s4];           // 16B-aligned LDS read
          __builtin_memcpy(ob + (size_t)o * NTOT + n0 + s4, &v, 16);
        } else {
          for (int vv = 0; vv < 4; ++vv)
            if (s4 + vv < valid)
              ob[(size_t)o * NTOT + n0 + s4 + vv] = os[o][s4 + vv];
        }
      }
    }
  } else {
    // ================= Region A: l < 32, verified R3 direct 16-chunk =================
    const int s = ((int)blockIdx.x - NWINB) * 4 + wv;     // 0..79
    int l, c;
    if (s < 8)       { l = s;                    c = 0; }
    else if (s < 24) { l = 8 + ((s - 8) >> 1);   c = (s - 8) & 1; }
    else if (s < 48) { l = 16 + (s - 24) / 3;    c = (s - 24) % 3; }
    else             { l = 24 + ((s - 48) >> 2); c = (s - 48) & 3; }
    const int P = 2 * l + 1;

    const int p  = c * 16 + m;
    const int pl = (p < P) ? p : (P - 1);                 // clamp tail loads
    const size_t nbase = (size_t)l * l;
    const float* xb = x + (size_t)b * CH * NTOT + nbase + pl;

    float xraw[16];
#pragma unroll
    for (int ks = 0; ks < 2; ++ks)
#pragma unroll
      for (int j = 0; j < 8; ++j)
        xraw[ks * 8 + j] = xb[(size_t)(ks * 32 + kg * 8 + j) * NTOT];

    bf16x8 bf[2];
#pragma unroll
    for (int ks = 0; ks < 2; ++ks)
#pragma unroll
      for (int j = 0; j < 8; ++j) {
        __hip_bfloat16 h = __float2bfloat16(xraw[ks * 8 + j]);
        bf[ks][j] = *reinterpret_cast<short*>(&h);
      }

    const __hip_bfloat16* wl = wtb + (size_t)l * 4096;
    f32x4 acc[4];
#pragma unroll
    for (int t = 0; t < 4; ++t) acc[t] = (f32x4)(0.0f);
#pragma unroll
    for (int ks = 0; ks < 2; ++ks) {
#pragma unroll
      for (int t = 0; t < 4; ++t) {
        const int o  = t * 16 + m;
        const int i0 = ks * 32 + kg * 8;
        bf16x8 afrag = *reinterpret_cast<const bf16x8*>(wl + (size_t)o * 64 + i0);
        acc[t] = __builtin_amdgcn_mfma_f32_16x16x32_bf16(afrag, bf[ks], acc[t], 0, 0, 0);
      }
    }

    if (p < P) {
      float* ob = out + (size_t)b * CH * NTOT + nbase + p;
#pragma unroll
      for (int t = 0; t < 4; ++t)
#pragma unroll
        for (int rg = 0; rg < 4; ++rg) {
          const int o = t * 16 + kg * 4 + rg;
          ob[(size_t)o * NTOT] = acc[t][rg];
        }
    }
  }
}

// ---- Fallback (no workspace): R2's passing fp32 LDS kernel ----
__global__ __launch_bounds__(192) void shconv_fallback(const float* __restrict__ x,
                                                       const float* __restrict__ w,
                                                       float* __restrict__ out) {
  __shared__ float wl[2][64][64];
  const int l1 = blockIdx.x;
  const int l2 = 80 - l1;
  const int P1 = 2 * l1 + 1;
  const int P2 = (l1 == 40) ? 0 : 2 * l2 + 1;
  int cp1, cp2; float f1, f2;
  if (l1 < 75) { cp1 = l1 / 5; f1 = (float)(l1 - cp1 * 5) * 0.2f; }
  else         { cp1 = 15;     f1 = (float)(l1 - 75) * 0.2f; }
  if (l2 < 75) { cp2 = l2 / 5; f2 = (float)(l2 - cp2 * 5) * 0.2f; }
  else         { cp2 = 15;     f2 = (float)(l2 - 75) * 0.2f; }
  const int tid = threadIdx.x;
  for (int e = tid; e < 8192; e += 192) {
    int sel = e >> 12, rr = e & 4095, i = rr >> 6, o = rr & 63;
    int cp = sel ? cp2 : cp1;
    float f = sel ? f2 : f1;
    const float* wp = w + (size_t)(i * 64 + o) * 17 + cp;
    wl[sel][i][o] = (1.0f - f) * wp[0] + f * wp[1];
  }
  __syncthreads();
  const int Ptot = P1 + P2;
  if (tid >= Ptot) return;
  int sel, l, p;
  if (tid < P1) { sel = 0; l = l1; p = tid; }
  else          { sel = 1; l = l2; p = tid - P1; }
  const size_t nidx = (size_t)(l * l) + p;
  const int b0 = blockIdx.y, b1 = b0 + 16;
  const float* x0 = x + (size_t)b0 * CH * NTOT + nidx;
  const float* x1 = x + (size_t)b1 * CH * NTOT + nidx;
  float acc0[64], acc1[64];
#pragma unroll
  for (int o = 0; o < 64; ++o) { acc0[o] = 0.f; acc1[o] = 0.f; }
  const float* wbase = &wl[sel][0][0];
#pragma unroll 4
  for (int i = 0; i < 64; ++i) {
    float xv0 = x0[(size_t)i * NTOT];
    float xv1 = x1[(size_t)i * NTOT];
    const float* wr = wbase + i * 64;
#pragma unroll
    for (int o = 0; o < 64; o += 4) {
      float4 wv = *(const float4*)(wr + o);
      acc0[o]     = fmaf(xv0, wv.x, acc0[o]);
      acc0[o + 1] = fmaf(xv0, wv.y, acc0[o + 1]);
      acc0[o + 2] = fmaf(xv0, wv.z, acc0[o + 2]);
      acc0[o + 3] = fmaf(xv0, wv.w, acc0[o + 3]);
      acc1[o]     = fmaf(xv1, wv.x, acc1[o]);
      acc1[o + 1] = fmaf(xv1, wv.y, acc1[o + 1]);
      acc1[o + 2] = fmaf(xv1, wv.z, acc1[o + 2]);
      acc1[o + 3] = fmaf(xv1, wv.w, acc1[o + 3]);
    }
  }
  float* o0 = out + (size_t)b0 * CH * NTOT + nidx;
  float* o1 = out + (size_t)b1 * CH * NTOT + nidx;
#pragma unroll
  for (int o = 0; o < 64; ++o) {
    o0[(size_t)o * NTOT] = acc0[o];
    o1[(size_t)o * NTOT] = acc1[o];
  }
}

extern "C" void kernel_launch(void* const* d_in, const int* in_sizes, int n_in,
                              void* d_out, int out_size, void* d_ws, size_t ws_size,
                              hipStream_t stream) {
  const float* x = (const float*)d_in[0];
  const float* w = (const float*)d_in[1];
  float* out = (float*)d_out;

  if (ws_size >= (size_t)WTB_BYTES && d_ws != nullptr) {
    __hip_bfloat16* wtb = (__hip_bfloat16*)d_ws;
    hipLaunchKernelGGL(interp_bf16, dim3(1296), dim3(256), 0, stream, w, wtb);
    hipLaunchKernelGGL(shconv_fused, dim3(GXT, 32), dim3(256), 0, stream, x, wtb, out);
  } else {
    hipLaunchKernelGGL(shconv_fallback, dim3(41, 16), dim3(192), 0, stream, x, w, out);
  }
}